// Round 10
// baseline (244.491 us; speedup 1.0000x reference)
//
#include <hip/hip_runtime.h>
#include <hip/hip_bf16.h>

#define B_ 4
#define D_ 128
#define H_ 128
#define W_ 32
#define CI 32
#define CO 64
#define OD 64
#define OH 64
#define OW 32
#define S_SPATIAL (OD*OH*OW)   // 131072
#define EPS 1e-5f
#define ALPHA 0.2f

#define ROWF 1024               // floats per ih row: 32 iw * 32 ci
#define XSLICEB (9*ROWF*4)      // 36864 B: 9 f32 rows (oh-quad kd-slice)
#define WCHUNKB 12288           // 3 taps x 4 nf x 512 shorts (one kh group)
#define PLANEF (H_*ROWF)        // floats per id plane

typedef __attribute__((ext_vector_type(8))) short short8;
typedef __attribute__((ext_vector_type(4))) float f32x4;
typedef __attribute__((ext_vector_type(4))) unsigned u32x4;

__device__ inline short f2bf(float f) {
    return __builtin_bit_cast(short, __float2bfloat16(f));   // RNE; pairs fuse to cvt_pk
}

__device__ inline short8 pack8(float4 a, float4 b) {
    short8 r;
    r[0]=f2bf(a.x); r[1]=f2bf(a.y); r[2]=f2bf(a.z); r[3]=f2bf(a.w);
    r[4]=f2bf(b.x); r[5]=f2bf(b.y); r[6]=f2bf(b.z); r[7]=f2bf(b.w);
    return r;
}

__device__ inline short8 mask_frag(short8 v, unsigned m) {
    u32x4 u = __builtin_bit_cast(u32x4, v);
    u[0]&=m; u[1]&=m; u[2]&=m; u[3]&=m;
    return __builtin_bit_cast(short8, u);
}

__device__ inline void gload16(const void* g, const void* l) {
    // async fire-and-forget 16B/lane global->LDS DMA (no dest VGPR -> can't be sunk)
    __builtin_amdgcn_global_load_lds(
        (const __attribute__((address_space(1))) void*)g,
        (__attribute__((address_space(3))) void*)l, 16, 0, 0);
}

__global__ __launch_bounds__(512) void zero_ws_kernel(float* ws) {
    ws[threadIdx.x] = 0.f;   // 512 floats: sums + sumsqs
}

// Repack w[b,kd,kh,kw,ci,co] f32 -> bf16 lane-ordered B-fragments: [b][tap][nf][512].
__global__ __launch_bounds__(64) void wprep_kernel(const float* __restrict__ w,
                                                   short* __restrict__ wp) {
    int blk = blockIdx.x;          // ((b*27+tap)*4+nf)
    int nf  = blk & 3;
    int tb  = blk >> 2;            // b*27+tap
    int l   = threadIdx.x;
    int l15 = l & 15, lhi = l >> 4;
    const float* wsrc = w + (size_t)tb * (CI*CO);   // [ci][co]
    short8 v;
#pragma unroll
    for (int j = 0; j < 8; ++j)
        v[j] = f2bf(wsrc[(lhi*8 + j)*CO + nf*16 + l15]);
    *(short8*)(wp + (size_t)blk*512 + l*8) = v;
}

#define VM0_BAR() \
    asm volatile("s_waitcnt vmcnt(0) lgkmcnt(0)" ::: "memory"); \
    __builtin_amdgcn_s_barrier(); \
    __builtin_amdgcn_sched_barrier(0)

#define BAR_ONLY() \
    __builtin_amdgcn_s_barrier(); \
    __builtin_amdgcn_sched_barrier(0)

// Implicit-GEMM conv. x: f32 kd-slice via DMA (XOR-swizzled source, single buffer).
// w: bf16 kh-chunks (12KB) via DMA, double-buffered -> 9 pipelined phases/block;
// chunk k+1's DMA rides under chunk k's 24 MFMA. Hot loop: LDS + MFMA only.
// Block = (b, od, oh-quad); wave wv owns oh row oh0+wv. Fused InstanceNorm stats.
__global__ __launch_bounds__(256, 2) void conv_mfma_kernel(const float* __restrict__ x,
                                                           const short* __restrict__ wp,
                                                           float* __restrict__ out,
                                                           float* __restrict__ ws) {
    const int bid = blockIdx.x;
    const int b   = bid >> 10;
    const int od  = (bid >> 4) & 63;
    const int oh0 = (bid & 15) << 2;
    const int t   = threadIdx.x;
    const int wv  = t >> 6;
    const int l   = t & 63;
    const int l15 = l & 15;
    const int lhi = l >> 4;

    const float* xb  = x + (size_t)b * (D_*PLANEF);
    const short* wpb = wp + (size_t)b * (27*2048);

    __shared__ __align__(16) char smem[XSLICEB + 2*WCHUNKB];   // 61440 B
    float* xbuf = (float*)smem;
    char*  wbuf0 = smem + XSLICEB;
    char*  wbuf1 = smem + XSLICEB + WCHUNKB;

    // x swizzle (R7-verified): lane source offset within a 256-float segment.
    // LDS[o] holds x[o ^ ((o>>5 & 7)<<2)] (involution on bits 2..4 keyed by 5..7).
    const int lnF = (l << 2) ^ ((l & 0x38) >> 1);
    const int seg = (t >> 6) & 3;            // wave's segment within a row

    // stage one 9-row f32 x slice (9 DMA instr; row k staged by all 4 waves)
    auto dma_x = [&](const float* plane) {
#pragma unroll
        for (int k = 0; k < 9; ++k) {
            int ih = oh0*2 + k; if (ih > H_-1) ih = H_-1;    // clamp; OOB never computed
            gload16(plane + (size_t)ih*ROWF + seg*256 + lnF,
                    xbuf + k*ROWF + seg*256);
        }
    };
    // stage one 3-tap w chunk (3 DMA instr)
    auto dma_w = [&](int chunk, char* wb) {
        const short* src = wpb + (size_t)chunk*6144;          // 3 taps contiguous
#pragma unroll
        for (int j = 0; j < 3; ++j)
            gload16(src + j*2048 + (t >> 6)*512 + l*8,
                    wb + j*4096 + (t >> 6)*1024);
    };

    f32x4 acc[2][4];
#pragma unroll
    for (int mf = 0; mf < 2; ++mf)
#pragma unroll
        for (int nf = 0; nf < 4; ++nf)
            acc[mf][nf] = (f32x4){0.f, 0.f, 0.f, 0.f};

    const unsigned mlo = (l15 == 0)  ? 0u : 0xFFFFFFFFu;  // kw=0, mf=0 W-edge
    const unsigned mhi = (l15 == 15) ? 0u : 0xFFFFFFFFu;  // kw=2, mf=1 W-edge
    const int ohw2 = 2*(oh0 + wv);

    // 3 taps (kw=0..2) of one kh from chunk buffer wb
    auto compute3 = [&](int kh, const char* wb) {
        const float* pr = xbuf + (2*wv + kh)*ROWF;
#pragma unroll
        for (int kw = 0; kw < 3; ++kw) {
            const char* wpt = wb + kw*4096 + l*16;
            short8 bf0 = *(const short8*)(wpt);
            short8 bf1 = *(const short8*)(wpt + 1024);
            short8 bf2 = *(const short8*)(wpt + 2048);
            short8 bf3 = *(const short8*)(wpt + 3072);
#pragma unroll
            for (int mf = 0; mf < 2; ++mf) {
                int iw = mf*16 + l15 + kw - 1;
                iw = iw < 0 ? 0 : (iw > 31 ? 31 : iw);
                int o  = iw*32 + lhi*8;
                int x4 = (iw & 7) << 2;
                float4 v0 = *(const float4*)(pr + (o ^ x4));
                float4 v1 = *(const float4*)(pr + ((o + 4) ^ x4));
                short8 a = pack8(v0, v1);
                if (kw == 0 && mf == 0) a = mask_frag(a, mlo);
                if (kw == 2 && mf == 1) a = mask_frag(a, mhi);
                acc[mf][0] = __builtin_amdgcn_mfma_f32_16x16x32_bf16(a, bf0, acc[mf][0], 0,0,0);
                acc[mf][1] = __builtin_amdgcn_mfma_f32_16x16x32_bf16(a, bf1, acc[mf][1], 0,0,0);
                acc[mf][2] = __builtin_amdgcn_mfma_f32_16x16x32_bf16(a, bf2, acc[mf][2], 0,0,0);
                acc[mf][3] = __builtin_amdgcn_mfma_f32_16x16x32_bf16(a, bf3, acc[mf][3], 0,0,0);
            }
        }
    };

    const int id0 = od*2;
    const bool has2 = (id0 + 2) < D_;
    const float* planes[3];
    planes[0] = xb + (size_t)id0 * PLANEF;
    planes[1] = planes[0] + PLANEF;                    // id0+1 <= 127 always
    planes[2] = has2 ? (planes[1] + PLANEF) : planes[1];   // clamped; never computed

    // prologue: x slice 0 + w chunk 0 in flight
    dma_x(planes[0]);
    dma_w(0, wbuf0);
    VM0_BAR();

    char* wb[2] = { wbuf0, wbuf1 };
#pragma unroll
    for (int kd = 0; kd < 3; ++kd) {
        const bool kd_ok = (kd < 2) || has2;           // block-uniform
#pragma unroll
        for (int kh = 0; kh < 3; ++kh) {
            const int c = kd*3 + kh;
            if (c + 1 < 9) dma_w(c + 1, wb[(c + 1) & 1]);   // next chunk in flight
            if (kd_ok && (ohw2 + kh) < H_)                  // wave-uniform H guard
                compute3(kh, wb[c & 1]);
            if (kh == 2 && kd < 2) {
                BAR_ONLY();                 // all waves' x reads consumed
                dma_x(planes[kd + 1]);      // overwrite xbuf
            }
            VM0_BAR();                      // next w chunk (and x at kd edge) ready
        }
    }

    // C-write. C/D: row = lhi*4 + r, col = l15 [m89]
    const int oh = oh0 + wv;
    float* yb = out + (size_t)((b*OD + od)*OH + oh) * (OW*CO);
#pragma unroll
    for (int mf = 0; mf < 2; ++mf)
#pragma unroll
        for (int nf = 0; nf < 4; ++nf)
#pragma unroll
            for (int r = 0; r < 4; ++r) {
                int ow = mf*16 + lhi*4 + r;
                int co = nf*16 + l15;
                yb[ow*CO + co] = acc[mf][nf][r];
            }

    // Fused InstanceNorm stats (LDS scratch aliases the tile after full drain)
    __syncthreads();
    float* lsum = (float*)smem;            // [4][64]
    float* lsq  = (float*)(smem + 1024);   // [4][64]
    float csum[4], csq[4];
#pragma unroll
    for (int nf = 0; nf < 4; ++nf) {
        float s = 0.f, q = 0.f;
#pragma unroll
        for (int mf = 0; mf < 2; ++mf)
#pragma unroll
            for (int r = 0; r < 4; ++r) {
                float v = acc[mf][nf][r];
                s += v;
                q = fmaf(v, v, q);
            }
        s += __shfl_xor(s, 16, 64); s += __shfl_xor(s, 32, 64);
        q += __shfl_xor(q, 16, 64); q += __shfl_xor(q, 32, 64);
        csum[nf] = s; csq[nf] = q;
    }
    if (lhi == 0) {
#pragma unroll
        for (int nf = 0; nf < 4; ++nf) {
            lsum[wv*64 + nf*16 + l15] = csum[nf];
            lsq[wv*64 + nf*16 + l15]  = csq[nf];
        }
    }
    __syncthreads();
    if (t < 64) {
        float s = lsum[t] + lsum[64 + t] + lsum[128 + t] + lsum[192 + t];
        float q = lsq[t]  + lsq[64 + t]  + lsq[128 + t]  + lsq[192 + t];
        atomicAdd(&ws[b*64 + t], s);
        atomicAdd(&ws[256 + b*64 + t], q);
    }
}

// ws[0..255]=sum, ws[256..511]=sumsq  ->  ws[512..767]=scale, ws[768..1023]=shift
__global__ __launch_bounds__(256) void finalize_kernel(float* ws,
                                                       const float* __restrict__ gamma,
                                                       const float* __restrict__ beta) {
    int t = threadIdx.x;       // t = b*64 + co
    int co = t & 63;
    const float invS = 1.0f / (float)S_SPATIAL;
    float sum = ws[t];
    float sq  = ws[256 + t];
    float mu  = sum * invS;
    float var = sq * invS - mu*mu;
    float scale = rsqrtf(var + EPS) * gamma[co];
    ws[512 + t] = scale;
    ws[768 + t] = beta[co] - mu*scale;
}

// In-place normalize + leaky relu, float4 per thread.
__global__ __launch_bounds__(256) void norm_kernel(float* __restrict__ y,
                                                   const float* __restrict__ ws) {
    size_t i = (size_t)blockIdx.x * 256 + threadIdx.x;  // float4 index, total 8388608
    int b = (int)(i >> 21);                              // 2097152 float4 per sample
    const float4* scp = (const float4*)(ws + 512 + b*64);
    const float4* shp = (const float4*)(ws + 768 + b*64);
    float4 sc = scp[i & 15];
    float4 sh = shp[i & 15];
    float4 v = ((const float4*)y)[i];
    float4 r;
    r.x = fmaf(v.x, sc.x, sh.x);
    r.y = fmaf(v.y, sc.y, sh.y);
    r.z = fmaf(v.z, sc.z, sh.z);
    r.w = fmaf(v.w, sc.w, sh.w);
    r.x = r.x >= 0.f ? r.x : ALPHA * r.x;
    r.y = r.y >= 0.f ? r.y : ALPHA * r.y;
    r.z = r.z >= 0.f ? r.z : ALPHA * r.z;
    r.w = r.w >= 0.f ? r.w : ALPHA * r.w;
    ((float4*)y)[i] = r;
}

extern "C" void kernel_launch(void* const* d_in, const int* in_sizes, int n_in,
                              void* d_out, int out_size, void* d_ws, size_t ws_size,
                              hipStream_t stream) {
    const float* x     = (const float*)d_in[0];
    const float* w     = (const float*)d_in[1];
    const float* gamma = (const float*)d_in[2];
    const float* beta  = (const float*)d_in[3];
    float* out = (float*)d_out;
    float* ws  = (float*)d_ws;
    short* wp  = (short*)((char*)d_ws + 4096);   // bf16 B-fragments (442368 B)

    zero_ws_kernel<<<1, 512, 0, stream>>>(ws);
    wprep_kernel<<<B_*27*4, 64, 0, stream>>>(w, wp);
    conv_mfma_kernel<<<B_*OD*(OH/4), 256, 0, stream>>>(x, wp, out, ws);
    finalize_kernel<<<1, 256, 0, stream>>>(ws, gamma, beta);
    norm_kernel<<<32768, 256, 0, stream>>>(out, ws);
}

// Round 11
// 232.248 us; speedup vs baseline: 1.0527x; 1.0527x over previous
//
#include <hip/hip_runtime.h>
#include <hip/hip_bf16.h>

#define B_ 4
#define D_ 128
#define H_ 128
#define W_ 32
#define CI 32
#define CO 64
#define OD 64
#define OH 64
#define OW 32
#define S_SPATIAL (OD*OH*OW)   // 131072
#define EPS 1e-5f
#define ALPHA 0.2f

#define XR 9                    // ih rows per kd-slice (oh-quad span)
#define XC 34                   // bf16 tile cols incl. W halo (c=iw+1, zero-padded)
#define UNITS (4*XR*XC)         // 1224 bf16 units of 16B
#define BFSLICE (UNITS*16)      // 19584 B
#define ROWF 1024               // floats per ih row (32 iw * 32 ci)
#define RAWB (XR*ROWF*4)        // 36864 B raw f32 slice
#define PLANEF (H_*ROWF)

typedef __attribute__((ext_vector_type(8))) short short8;
typedef __attribute__((ext_vector_type(4))) float f32x4;

__device__ inline short f2bf(float f) {
    return __builtin_bit_cast(short, __float2bfloat16(f));   // RNE; pairs fuse to cvt_pk
}

__device__ inline short8 pack8(float4 a, float4 b) {
    short8 r;
    r[0]=f2bf(a.x); r[1]=f2bf(a.y); r[2]=f2bf(a.z); r[3]=f2bf(a.w);
    r[4]=f2bf(b.x); r[5]=f2bf(b.y); r[6]=f2bf(b.z); r[7]=f2bf(b.w);
    return r;
}

__device__ inline void gload16(const void* g, const void* l) {
    // async fire-and-forget 16B/lane global->LDS DMA (no dest VGPR -> unsinkable)
    __builtin_amdgcn_global_load_lds(
        (const __attribute__((address_space(1))) void*)g,
        (__attribute__((address_space(3))) void*)l, 16, 0, 0);
}

__global__ __launch_bounds__(512) void zero_ws_kernel(float* ws) {
    ws[threadIdx.x] = 0.f;   // 512 floats: sums + sumsqs
}

// Repack w[b,kd,kh,kw,ci,co] f32 -> bf16 lane-ordered B-fragments: [b][tap][nf][512].
__global__ __launch_bounds__(64) void wprep_kernel(const float* __restrict__ w,
                                                   short* __restrict__ wp) {
    int blk = blockIdx.x;          // ((b*27+tap)*4+nf)
    int nf  = blk & 3;
    int tb  = blk >> 2;            // b*27+tap
    int l   = threadIdx.x;
    int l15 = l & 15, lhi = l >> 4;
    const float* wsrc = w + (size_t)tb * (CI*CO);   // [ci][co]
    short8 v;
#pragma unroll
    for (int j = 0; j < 8; ++j)
        v[j] = f2bf(wsrc[(lhi*8 + j)*CO + nf*16 + l15]);
    *(short8*)(wp + (size_t)blk*512 + l*8) = v;
}

#define BAR_VM0() \
    asm volatile("s_waitcnt vmcnt(0) lgkmcnt(0)" ::: "memory"); \
    __builtin_amdgcn_s_barrier(); \
    __builtin_amdgcn_sched_barrier(0)

#define BAR_LGKM() \
    asm volatile("s_waitcnt lgkmcnt(0)" ::: "memory"); \
    __builtin_amdgcn_s_barrier(); \
    __builtin_amdgcn_sched_barrier(0)

// Implicit-GEMM conv, 3-phase pipelined per kd-slice:
//   DMA raw f32 slice (swizzled source, under prev compute) ->
//   LDS->LDS repack (cvt + halo/OOB zero, cheap) ->
//   pure bf16 hot loop (2 A ds_read + 4 B global(L1) + 8 MFMA per tap, no guards).
// No memory-stalled barrier: every vmcnt(0) is a full compute phase after its DMA.
// Block = (b, od, oh-quad); wave wv owns oh row oh0+wv. Fused InstanceNorm stats.
__global__ __launch_bounds__(256, 2) void conv_mfma_kernel(const float* __restrict__ x,
                                                           const short* __restrict__ wp,
                                                           float* __restrict__ out,
                                                           float* __restrict__ ws) {
    const int bid = blockIdx.x;
    const int b   = bid >> 10;
    const int od  = (bid >> 4) & 63;
    const int oh0 = (bid & 15) << 2;
    const int t   = threadIdx.x;
    const int wv  = t >> 6;
    const int l   = t & 63;
    const int l15 = l & 15;
    const int lhi = l >> 4;

    const float* xb  = x + (size_t)b * (D_*PLANEF);
    const short* wpb = wp + (size_t)b * (27*2048);

    __shared__ __align__(16) char smem[RAWB + 2*BFSLICE];   // 76032 B
    float* raw = (float*)smem;
    char*  bf0 = smem + RAWB;
    char*  bf1 = smem + RAWB + BFSLICE;

    // DMA: wave wv owns segment wv of each row; source pre-swizzled (R7-verified):
    // raw[o] = x[o ^ ((o>>5&7)<<2)] within each 256-float segment.
    const int lnF = (l << 2) ^ ((l & 0x38) >> 1);
    auto dma_x = [&](const float* plane) {
#pragma unroll
        for (int k = 0; k < XR; ++k) {
            int ih = oh0*2 + k; if (ih > H_-1) ih = H_-1;   // clamp; zeroed at repack
            gload16(plane + (size_t)ih*ROWF + wv*256 + lnF,
                    raw + k*ROWF + wv*256);
        }
    };

    // repack raw f32 -> halo-padded bf16 tile [g][r][c]; zero W-halo and OOB-H rows
    auto repack = [&](char* dst) {
#pragma unroll
        for (int k = 0; k < 5; ++k) {
            int U = t + (k << 8);
            if (U < UNITS) {
                int g   = U / (XR*XC);
                int rem = U % (XR*XC);
                int r   = rem / XC;
                int c   = rem % XC;
                int iw  = c - 1;
                short8 v = (short8){0,0,0,0,0,0,0,0};
                if ((unsigned)iw < (unsigned)W_ && (oh0*2 + r) < H_) {
                    int o  = r*ROWF + iw*32 + g*8;
                    int sw = (iw & 7) << 2;               // same XOR as DMA source
                    float4 a = *(const float4*)(raw + (o ^ sw));
                    float4 bq = *(const float4*)(raw + ((o + 4) ^ sw));
                    v = pack8(a, bq);
                }
                *(short8*)(dst + U*16) = v;
            }
        }
    };

    f32x4 acc[2][4];
#pragma unroll
    for (int mf = 0; mf < 2; ++mf)
#pragma unroll
        for (int nf = 0; nf < 4; ++nf)
            acc[mf][nf] = (f32x4){0.f, 0.f, 0.f, 0.f};

    // hot loop: no conditionals (halo & OOB rows are zero in the bf16 tile)
    auto compute = [&](int kd, const char* base) {
        const short* wkd = wpb + (size_t)kd*(9*2048) + l*8;
#pragma unroll
        for (int kh = 0; kh < 3; ++kh) {
            const int r = 2*wv + kh;
#pragma unroll
            for (int kw = 0; kw < 3; ++kw) {
                const short* wpt = wkd + (kh*3 + kw)*2048;
                short8 bq0 = *(const short8*)(wpt);
                short8 bq1 = *(const short8*)(wpt + 512);
                short8 bq2 = *(const short8*)(wpt + 1024);
                short8 bq3 = *(const short8*)(wpt + 1536);
#pragma unroll
                for (int mf = 0; mf < 2; ++mf) {
                    int c = mf*16 + l15 + kw;
                    int U = (lhi*XR + r)*XC + c;
                    short8 a = *(const short8*)(base + U*16);
                    acc[mf][0] = __builtin_amdgcn_mfma_f32_16x16x32_bf16(a, bq0, acc[mf][0], 0,0,0);
                    acc[mf][1] = __builtin_amdgcn_mfma_f32_16x16x32_bf16(a, bq1, acc[mf][1], 0,0,0);
                    acc[mf][2] = __builtin_amdgcn_mfma_f32_16x16x32_bf16(a, bq2, acc[mf][2], 0,0,0);
                    acc[mf][3] = __builtin_amdgcn_mfma_f32_16x16x32_bf16(a, bq3, acc[mf][3], 0,0,0);
                }
            }
        }
    };

    const int id0 = od*2;
    const bool has2 = (id0 + 2) < D_;
    const float* p0 = xb + (size_t)id0 * PLANEF;
    const float* p1 = p0 + PLANEF;                 // id0+1 <= 127 always
    const float* p2 = has2 ? (p1 + PLANEF) : p1;   // clamped; never computed

    // pipeline: DMA k+1 always rides under compute k; no stalled waits
    dma_x(p0);
    BAR_VM0();                  // raw=slice0 (prologue latency exposed once)
    repack(bf0);
    BAR_LGKM();                 // bf0 visible; raw reads done
    dma_x(p1);                  // in flight under compute(0)
    compute(0, bf0);
    BAR_VM0();                  // raw=slice1 (landed during compute); bf-writes none
    repack(bf1);
    BAR_LGKM();                 // bf1 visible; raw reads done
    dma_x(p2);                  // in flight under compute(1)
    compute(1, bf1);
    BAR_VM0();                  // raw=slice2
    repack(bf0);                // bf0 free since compute(0)
    BAR_LGKM();
    if (has2) compute(2, bf0);  // block-uniform guard

    // C-write. C/D: row = lhi*4 + r, col = l15 [m89]
    const int oh = oh0 + wv;
    float* yb = out + (size_t)((b*OD + od)*OH + oh) * (OW*CO);
#pragma unroll
    for (int mf = 0; mf < 2; ++mf)
#pragma unroll
        for (int nf = 0; nf < 4; ++nf)
#pragma unroll
            for (int r = 0; r < 4; ++r) {
                int ow = mf*16 + lhi*4 + r;
                int co = nf*16 + l15;
                yb[ow*CO + co] = acc[mf][nf][r];
            }

    // Fused InstanceNorm stats (scratch aliases raw region after full drain)
    __syncthreads();
    float* lsum = (float*)smem;            // [4][64]
    float* lsq  = (float*)(smem + 1024);   // [4][64]
    float csum[4], csq[4];
#pragma unroll
    for (int nf = 0; nf < 4; ++nf) {
        float s = 0.f, q = 0.f;
#pragma unroll
        for (int mf = 0; mf < 2; ++mf)
#pragma unroll
            for (int r = 0; r < 4; ++r) {
                float v = acc[mf][nf][r];
                s += v;
                q = fmaf(v, v, q);
            }
        s += __shfl_xor(s, 16, 64); s += __shfl_xor(s, 32, 64);
        q += __shfl_xor(q, 16, 64); q += __shfl_xor(q, 32, 64);
        csum[nf] = s; csq[nf] = q;
    }
    if (lhi == 0) {
#pragma unroll
        for (int nf = 0; nf < 4; ++nf) {
            lsum[wv*64 + nf*16 + l15] = csum[nf];
            lsq[wv*64 + nf*16 + l15]  = csq[nf];
        }
    }
    __syncthreads();
    if (t < 64) {
        float s = lsum[t] + lsum[64 + t] + lsum[128 + t] + lsum[192 + t];
        float q = lsq[t]  + lsq[64 + t]  + lsq[128 + t]  + lsq[192 + t];
        atomicAdd(&ws[b*64 + t], s);
        atomicAdd(&ws[256 + b*64 + t], q);
    }
}

// ws[0..255]=sum, ws[256..511]=sumsq  ->  ws[512..767]=scale, ws[768..1023]=shift
__global__ __launch_bounds__(256) void finalize_kernel(float* ws,
                                                       const float* __restrict__ gamma,
                                                       const float* __restrict__ beta) {
    int t = threadIdx.x;       // t = b*64 + co
    int co = t & 63;
    const float invS = 1.0f / (float)S_SPATIAL;
    float sum = ws[t];
    float sq  = ws[256 + t];
    float mu  = sum * invS;
    float var = sq * invS - mu*mu;
    float scale = rsqrtf(var + EPS) * gamma[co];
    ws[512 + t] = scale;
    ws[768 + t] = beta[co] - mu*scale;
}

// In-place normalize + leaky relu, float4 per thread.
__global__ __launch_bounds__(256) void norm_kernel(float* __restrict__ y,
                                                   const float* __restrict__ ws) {
    size_t i = (size_t)blockIdx.x * 256 + threadIdx.x;  // float4 index, total 8388608
    int b = (int)(i >> 21);                              // 2097152 float4 per sample
    const float4* scp = (const float4*)(ws + 512 + b*64);
    const float4* shp = (const float4*)(ws + 768 + b*64);
    float4 sc = scp[i & 15];
    float4 sh = shp[i & 15];
    float4 v = ((const float4*)y)[i];
    float4 r;
    r.x = fmaf(v.x, sc.x, sh.x);
    r.y = fmaf(v.y, sc.y, sh.y);
    r.z = fmaf(v.z, sc.z, sh.z);
    r.w = fmaf(v.w, sc.w, sh.w);
    r.x = r.x >= 0.f ? r.x : ALPHA * r.x;
    r.y = r.y >= 0.f ? r.y : ALPHA * r.y;
    r.z = r.z >= 0.f ? r.z : ALPHA * r.z;
    r.w = r.w >= 0.f ? r.w : ALPHA * r.w;
    ((float4*)y)[i] = r;
}

extern "C" void kernel_launch(void* const* d_in, const int* in_sizes, int n_in,
                              void* d_out, int out_size, void* d_ws, size_t ws_size,
                              hipStream_t stream) {
    const float* x     = (const float*)d_in[0];
    const float* w     = (const float*)d_in[1];
    const float* gamma = (const float*)d_in[2];
    const float* beta  = (const float*)d_in[3];
    float* out = (float*)d_out;
    float* ws  = (float*)d_ws;
    short* wp  = (short*)((char*)d_ws + 4096);   // bf16 B-fragments (442368 B)

    zero_ws_kernel<<<1, 512, 0, stream>>>(ws);
    wprep_kernel<<<B_*27*4, 64, 0, stream>>>(w, wp);
    conv_mfma_kernel<<<B_*OD*(OH/4), 256, 0, stream>>>(x, wp, out, ws);
    finalize_kernel<<<1, 256, 0, stream>>>(ws, gamma, beta);
    norm_kernel<<<32768, 256, 0, stream>>>(out, ws);
}

// Round 12
// 218.524 us; speedup vs baseline: 1.1188x; 1.0628x over previous
//
#include <hip/hip_runtime.h>
#include <hip/hip_bf16.h>

#define B_ 4
#define D_ 128
#define H_ 128
#define W_ 32
#define CI 32
#define CO 64
#define OD 64
#define OH 64
#define OW 32
#define S_SPATIAL (OD*OH*OW)   // 131072
#define EPS 1e-5f
#define ALPHA 0.2f

#define XR 17                   // ih rows per kd-slice (oh-octet span)
#define XC 34                   // cols incl. W halo (c = iw+1, zero-padded)
#define UNITS (4*XR*XC)         // 2312 units of 8 bf16 (16B)
#define PLANEF (H_*W_*CI)       // floats per id plane

typedef __attribute__((ext_vector_type(8))) short short8;
typedef __attribute__((ext_vector_type(4))) float f32x4;

__device__ inline short f2bf(float f) {
    return __builtin_bit_cast(short, __float2bfloat16(f));   // RNE; pairs fuse to cvt_pk
}

__device__ inline short8 pack8(float4 a, float4 b) {
    short8 r;
    r[0]=f2bf(a.x); r[1]=f2bf(a.y); r[2]=f2bf(a.z); r[3]=f2bf(a.w);
    r[4]=f2bf(b.x); r[5]=f2bf(b.y); r[6]=f2bf(b.z); r[7]=f2bf(b.w);
    return r;
}

__global__ __launch_bounds__(512) void zero_ws_kernel(float* ws) {
    ws[threadIdx.x] = 0.f;   // 512 floats: sums + sumsqs
}

// Repack w[b,kd,kh,kw,ci,co] f32 -> bf16 lane-ordered B-fragments: [b][tap][nf][512].
__global__ __launch_bounds__(64) void wprep_kernel(const float* __restrict__ w,
                                                   short* __restrict__ wp) {
    int blk = blockIdx.x;          // ((b*27+tap)*4+nf)
    int nf  = blk & 3;
    int tb  = blk >> 2;            // b*27+tap
    int l   = threadIdx.x;
    int l15 = l & 15, lhi = l >> 4;
    const float* wsrc = w + (size_t)tb * (CI*CO);   // [ci][co]
    short8 v;
#pragma unroll
    for (int j = 0; j < 8; ++j)
        v[j] = f2bf(wsrc[(lhi*8 + j)*CO + nf*16 + l15]);
    *(short8*)(wp + (size_t)blk*512 + l*8) = v;
}

// R4 structure, code-compact: runtime loops, hoisted stage coords, incremental
// addressing. Block = (b, od, oh-octet); wave wv owns oh rows oh0+2wv, +1 (M=64).
// bf16 halo tile in LDS (no masks/guards in hot loop). Fused InstanceNorm stats.
__global__ __launch_bounds__(256) void conv_mfma_kernel(const float* __restrict__ x,
                                                        const short* __restrict__ wp,
                                                        float* __restrict__ out,
                                                        float* __restrict__ ws) {
    const int bid = blockIdx.x;
    const int b   = bid >> 9;
    const int od  = (bid >> 3) & 63;
    const int oh0 = (bid & 7) << 3;
    const int t   = threadIdx.x;
    const int wv  = t >> 6;
    const int l   = t & 63;
    const int l15 = l & 15;
    const int lhi = l >> 4;

    const float* xb  = x + (size_t)b * (D_*PLANEF);
    const short* wpb = wp + (size_t)b * (27*2048);

    __shared__ short xlds[UNITS*8];   // 36992 B, [g][r][c] 8-ci bf16 units
    __shared__ float lsum[4][64];
    __shared__ float lsq[4][64];

    // stage coords hoisted (slice-invariant): unit U = t + k*256 -> [g][r][c]
    int soff[10];
#pragma unroll
    for (int k = 0; k < 10; ++k) {
        int U   = t + (k << 8);
        int g   = U / (XR*XC);
        int rem = U % (XR*XC);
        int r   = rem / XC;
        int c   = rem % XC;
        int ih  = oh0*2 + r;
        int iw  = c - 1;
        soff[k] = (U < UNITS && ih < H_ && (unsigned)iw < (unsigned)W_)
                    ? (ih*(W_*CI) + iw*CI + g*8) : -1;
    }

    f32x4 acc[4][4];
#pragma unroll
    for (int mf = 0; mf < 4; ++mf)
#pragma unroll
        for (int nf = 0; nf < 4; ++nf)
            acc[mf][nf] = (f32x4){0.f, 0.f, 0.f, 0.f};

    // A-frag base for this lane: unit (lhi*XR + 4wv)*XC + l15, bytes
    const char* abase = (const char*)xlds + (((lhi*XR + 4*wv)*XC + l15) * 16);

    for (int kd = 0; kd < 3; ++kd) {
        const int id = od*2 + kd;
        if (id >= D_) break;                         // block-uniform (od=63 only)
        const float* xsl = xb + (size_t)id * PLANEF;

        __syncthreads();                             // prev slice's reads done
#pragma unroll
        for (int k = 0; k < 10; ++k) {
            int U = t + (k << 8);
            if (U < UNITS) {
                short8 v = (short8){0,0,0,0,0,0,0,0};
                if (soff[k] >= 0)
                    v = pack8(*(const float4*)(xsl + soff[k]),
                              *(const float4*)(xsl + soff[k] + 4));
                *(short8*)(xlds + (size_t)U*8) = v;
            }
        }
        __syncthreads();

        const short* wtap = wpb + (size_t)kd*(9*2048) + l*8;
#pragma unroll 1
        for (int kh = 0; kh < 3; ++kh) {             // compact runtime loop
            const char* pa = abase + (kh*XC)*16;
#pragma unroll
            for (int kw = 0; kw < 3; ++kw) {
                const short* wpt = wtap + kw*2048;
                short8 bf0 = *(const short8*)(wpt);
                short8 bf1 = *(const short8*)(wpt + 512);
                short8 bf2 = *(const short8*)(wpt + 1024);
                short8 bf3 = *(const short8*)(wpt + 1536);
                short8 a0 = *(const short8*)(pa + kw*16);            // rowA, ow0-15
                short8 a1 = *(const short8*)(pa + kw*16 + 256);      // rowA, ow16-31
                short8 a2 = *(const short8*)(pa + kw*16 + 2*XC*16);  // rowB, ow0-15
                short8 a3 = *(const short8*)(pa + kw*16 + 2*XC*16 + 256);
                acc[0][0] = __builtin_amdgcn_mfma_f32_16x16x32_bf16(a0, bf0, acc[0][0], 0,0,0);
                acc[0][1] = __builtin_amdgcn_mfma_f32_16x16x32_bf16(a0, bf1, acc[0][1], 0,0,0);
                acc[0][2] = __builtin_amdgcn_mfma_f32_16x16x32_bf16(a0, bf2, acc[0][2], 0,0,0);
                acc[0][3] = __builtin_amdgcn_mfma_f32_16x16x32_bf16(a0, bf3, acc[0][3], 0,0,0);
                acc[1][0] = __builtin_amdgcn_mfma_f32_16x16x32_bf16(a1, bf0, acc[1][0], 0,0,0);
                acc[1][1] = __builtin_amdgcn_mfma_f32_16x16x32_bf16(a1, bf1, acc[1][1], 0,0,0);
                acc[1][2] = __builtin_amdgcn_mfma_f32_16x16x32_bf16(a1, bf2, acc[1][2], 0,0,0);
                acc[1][3] = __builtin_amdgcn_mfma_f32_16x16x32_bf16(a1, bf3, acc[1][3], 0,0,0);
                acc[2][0] = __builtin_amdgcn_mfma_f32_16x16x32_bf16(a2, bf0, acc[2][0], 0,0,0);
                acc[2][1] = __builtin_amdgcn_mfma_f32_16x16x32_bf16(a2, bf1, acc[2][1], 0,0,0);
                acc[2][2] = __builtin_amdgcn_mfma_f32_16x16x32_bf16(a2, bf2, acc[2][2], 0,0,0);
                acc[2][3] = __builtin_amdgcn_mfma_f32_16x16x32_bf16(a2, bf3, acc[2][3], 0,0,0);
                acc[3][0] = __builtin_amdgcn_mfma_f32_16x16x32_bf16(a3, bf0, acc[3][0], 0,0,0);
                acc[3][1] = __builtin_amdgcn_mfma_f32_16x16x32_bf16(a3, bf1, acc[3][1], 0,0,0);
                acc[3][2] = __builtin_amdgcn_mfma_f32_16x16x32_bf16(a3, bf2, acc[3][2], 0,0,0);
                acc[3][3] = __builtin_amdgcn_mfma_f32_16x16x32_bf16(a3, bf3, acc[3][3], 0,0,0);
            }
            wtap += 6144;
        }
    }

    // C-write. C/D: row = lhi*4 + r, col = l15 [m89]
    const int ohA = oh0 + wv*2;
    float* ybA = out + (size_t)((b*OD + od)*OH + ohA) * (OW*CO);
#pragma unroll
    for (int mf = 0; mf < 4; ++mf) {
        float* yb = ybA + (size_t)(mf >> 1) * (OW*CO);
#pragma unroll
        for (int nf = 0; nf < 4; ++nf)
#pragma unroll
            for (int r = 0; r < 4; ++r) {
                int ow = (mf & 1)*16 + lhi*4 + r;
                int co = nf*16 + l15;
                yb[ow*CO + co] = acc[mf][nf][r];
            }
    }

    // Fused InstanceNorm stats
    float csum[4], csq[4];
#pragma unroll
    for (int nf = 0; nf < 4; ++nf) {
        float s = 0.f, q = 0.f;
#pragma unroll
        for (int mf = 0; mf < 4; ++mf)
#pragma unroll
            for (int r = 0; r < 4; ++r) {
                float v = acc[mf][nf][r];
                s += v;
                q = fmaf(v, v, q);
            }
        s += __shfl_xor(s, 16, 64); s += __shfl_xor(s, 32, 64);
        q += __shfl_xor(q, 16, 64); q += __shfl_xor(q, 32, 64);
        csum[nf] = s; csq[nf] = q;
    }
    if (lhi == 0) {
#pragma unroll
        for (int nf = 0; nf < 4; ++nf) {
            lsum[wv][nf*16 + l15] = csum[nf];
            lsq[wv][nf*16 + l15]  = csq[nf];
        }
    }
    __syncthreads();
    if (t < 64) {
        float s = lsum[0][t] + lsum[1][t] + lsum[2][t] + lsum[3][t];
        float q = lsq[0][t]  + lsq[1][t]  + lsq[2][t]  + lsq[3][t];
        atomicAdd(&ws[b*64 + t], s);
        atomicAdd(&ws[256 + b*64 + t], q);
    }
}

// ws[0..255]=sum, ws[256..511]=sumsq  ->  ws[512..767]=scale, ws[768..1023]=shift
__global__ __launch_bounds__(256) void finalize_kernel(float* ws,
                                                       const float* __restrict__ gamma,
                                                       const float* __restrict__ beta) {
    int t = threadIdx.x;       // t = b*64 + co
    int co = t & 63;
    const float invS = 1.0f / (float)S_SPATIAL;
    float sum = ws[t];
    float sq  = ws[256 + t];
    float mu  = sum * invS;
    float var = sq * invS - mu*mu;
    float scale = rsqrtf(var + EPS) * gamma[co];
    ws[512 + t] = scale;
    ws[768 + t] = beta[co] - mu*scale;
}

// In-place normalize + leaky relu, float4 per thread.
__global__ __launch_bounds__(256) void norm_kernel(float* __restrict__ y,
                                                   const float* __restrict__ ws) {
    size_t i = (size_t)blockIdx.x * 256 + threadIdx.x;  // float4 index, total 8388608
    int b = (int)(i >> 21);                              // 2097152 float4 per sample
    const float4* scp = (const float4*)(ws + 512 + b*64);
    const float4* shp = (const float4*)(ws + 768 + b*64);
    float4 sc = scp[i & 15];
    float4 sh = shp[i & 15];
    float4 v = ((const float4*)y)[i];
    float4 r;
    r.x = fmaf(v.x, sc.x, sh.x);
    r.y = fmaf(v.y, sc.y, sh.y);
    r.z = fmaf(v.z, sc.z, sh.z);
    r.w = fmaf(v.w, sc.w, sh.w);
    r.x = r.x >= 0.f ? r.x : ALPHA * r.x;
    r.y = r.y >= 0.f ? r.y : ALPHA * r.y;
    r.z = r.z >= 0.f ? r.z : ALPHA * r.z;
    r.w = r.w >= 0.f ? r.w : ALPHA * r.w;
    ((float4*)y)[i] = r;
}

extern "C" void kernel_launch(void* const* d_in, const int* in_sizes, int n_in,
                              void* d_out, int out_size, void* d_ws, size_t ws_size,
                              hipStream_t stream) {
    const float* x     = (const float*)d_in[0];
    const float* w     = (const float*)d_in[1];
    const float* gamma = (const float*)d_in[2];
    const float* beta  = (const float*)d_in[3];
    float* out = (float*)d_out;
    float* ws  = (float*)d_ws;
    short* wp  = (short*)((char*)d_ws + 4096);   // bf16 B-fragments (442368 B)

    zero_ws_kernel<<<1, 512, 0, stream>>>(ws);
    wprep_kernel<<<B_*27*4, 64, 0, stream>>>(w, wp);
    conv_mfma_kernel<<<B_*OD*(OH/8), 256, 0, stream>>>(x, wp, out, ws);
    finalize_kernel<<<1, 256, 0, stream>>>(ws, gamma, beta);
    norm_kernel<<<32768, 256, 0, stream>>>(out, ws);
}